// Round 2
// baseline (229.032 us; speedup 1.0000x reference)
//
#include <hip/hip_runtime.h>

// IDWT 2D (Haar-style 2x2 filter bank), R6 (= R5 resubmitted; rounds 0-1 were
// infra failures with no data, so no unmeasured changes stacked on top).
//
// Output layout identity: out float offset = nc*65536 + (i*128+j)*4 + ab
//                                          = 4 * (flat pixel index p) + ab.
// So the output is exactly float4[p]. We exploit this for perfect coalescing:
//   - wave handles a 256-pixel chunk [base, base+256) (always within one nc),
//   - lane L owns pixels p = base + t*64 + L, t=0..3,
//   - loads : 16x global_load_dword, each instruction 256 B wave-contiguous,
//   - stores: 4x global_store_dwordx4, each instruction 1 KiB wave-contiguous.
//
// R4 -> R5/R6 changes (theory: 225 us vs ~43 us roofline was NOT memory-bound):
//   1. Dropped __builtin_nontemporal_store (suspect: NT defeats L2 write
//      merging of 16 B lane-writes -> WRITE_SIZE inflation / partial lines).
//   2. 4 pixels/thread: 4x fewer threads, 16 loads in flight per thread,
//      amortized addressing.

typedef float floatx4 __attribute__((ext_vector_type(4)));

constexpr int B  = 8;
constexpr int C  = 64;   // C4/4
constexpr int H  = 128;
constexpr int W  = 128;
constexpr long PLANE_IN   = (long)H * W;         // 16384
constexpr long SUB_STRIDE = (long)C * PLANE_IN;  // 1,048,576 floats (4 MiB)
constexpr long P_TOTAL    = (long)B * C * H * W; // 8,388,608 pixels

__global__ __launch_bounds__(256) void idwt2d_kernel(
    const float* __restrict__ x,
    const float* __restrict__ f,
    float* __restrict__ out)
{
    const int lane = threadIdx.x & 63;
    const int wv   = threadIdx.x >> 6;
    // Wave chunk: 256 pixels; block (4 waves): 1024 pixels.
    const long p0 = (long)blockIdx.x * 1024 + (long)wv * 256 + lane;

    // Filters: wave-uniform, 4x float4 loads (L1-broadcast).
    floatx4 fv4[4];
#pragma unroll
    for (int k = 0; k < 4; ++k)
        fv4[k] = ((const floatx4*)f)[k];

    // n = p0 / (C*H*W); subband k lives at p + (3n + k)*SUB_STRIDE.
    const long n = p0 >> 20;
    const float* xb[4];
#pragma unroll
    for (int k = 0; k < 4; ++k)
        xb[k] = x + p0 + (3 * n + k) * SUB_STRIDE;

    // 16 loads: k-major so each subband's 4 slots (1 KiB region) issue together.
    // Each instruction: 64 lanes * 4 B contiguous, imm offsets 0/256/512/768 B.
    float v[4][4];
#pragma unroll
    for (int k = 0; k < 4; ++k)
#pragma unroll
        for (int t = 0; t < 4; ++t)
            v[t][k] = xb[k][t * 64];

    // Compute + store: 4x dwordx4, each instruction 1 KiB wave-contiguous.
    floatx4* o4 = (floatx4*)out + p0;
#pragma unroll
    for (int t = 0; t < 4; ++t) {
        floatx4 r;
#pragma unroll
        for (int ab = 0; ab < 4; ++ab) {
            float acc = fv4[0][ab] * v[t][0];
            acc += fv4[1][ab] * v[t][1];
            acc += fv4[2][ab] * v[t][2];
            acc += fv4[3][ab] * v[t][3];
            r[ab] = acc;
        }
        o4[t * 64] = r;
    }
}

extern "C" void kernel_launch(void* const* d_in, const int* in_sizes, int n_in,
                              void* d_out, int out_size, void* d_ws, size_t ws_size,
                              hipStream_t stream)
{
    const float* x   = (const float*)d_in[0];
    const float* flt = (const float*)d_in[1];
    float* out       = (float*)d_out;

    // 2,097,152 threads (4 pixels each) -> 8192 blocks x 256.
    const int block = 256;
    const int grid  = (int)(P_TOTAL / ((long)block * 4));
    idwt2d_kernel<<<grid, block, 0, stream>>>(x, flt, out);
}